// Round 5
// baseline (18082.320 us; speedup 1.0000x reference)
//
#include <hip/hip_runtime.h>

typedef unsigned short u16;
typedef unsigned int u32;
typedef __attribute__((ext_vector_type(8))) short shortx8;
typedef __attribute__((ext_vector_type(4))) float floatx4;
typedef __attribute__((ext_vector_type(4))) u32 uintx4;

#define AS1 __attribute__((address_space(1)))
#define AS3 __attribute__((address_space(3)))

__device__ __forceinline__ float bf2f(u16 u) {
  return __builtin_bit_cast(float, ((u32)u) << 16);
}
__device__ __forceinline__ u16 f2bf(float f) {
  u32 i = __builtin_bit_cast(u32, f);
  u32 r = (i + 0x7fffu + ((i >> 16) & 1u)) >> 16;  // RNE
  return (u16)r;
}

// ---------------------------------------------------------------------------
// Weight packing: QKV (fp32) -> Bt[l][n][k] bf16 (n = which*1024 + h*64 + d),
// bias fp32.
// ---------------------------------------------------------------------------
__launch_bounds__(256)
__global__ void pack_qkv(const float* __restrict__ Wq, const float* __restrict__ Wk,
                         const float* __restrict__ Wv, const float* __restrict__ bq,
                         const float* __restrict__ bk, const float* __restrict__ bv,
                         u16* __restrict__ Bt, float* __restrict__ bias) {
  const size_t i = (size_t)blockIdx.x * 256 + threadIdx.x;  // [l][n][k], 2*3072*1024
  const int k = (int)(i & 1023);
  const size_t r = i >> 10;
  const int n = (int)(r % 3072);
  const int l = (int)(r / 3072);
  const int which = n >> 10;
  const int nn = n & 1023;
  const int hh = nn >> 6, dd = nn & 63;
  const float* src = (which == 0) ? Wq : (which == 1) ? Wk : Wv;
  const float* srcb = (which == 0) ? bq : (which == 1) ? bk : bv;
  float v = src[(((size_t)l * 16 + hh) * 1024 + k) * 64 + dd];  // W[l][h][k][d]
  Bt[i] = f2bf(v);
  if (k == 0) bias[(size_t)l * 3072 + n] = srcb[(size_t)l * 1024 + nn];
}

// W[l][k][n] fp32 -> Bt[l][n][k] bf16   (for Wo, W1, W2)
__launch_bounds__(256)
__global__ void pack_t(const float* __restrict__ W, u16* __restrict__ Bt) {
  const size_t i = (size_t)blockIdx.x * 256 + threadIdx.x;  // [l][n][k], 2*1024*1024
  const int k = (int)(i & 1023);
  const size_t r = i >> 10;
  const int n = (int)(r & 1023);
  const int l = (int)(r >> 10);
  Bt[i] = f2bf(W[((size_t)l * 1024 + k) * 1024 + n]);
}

// ---------------------------------------------------------------------------
// enc_in: h[m][n] = x[m][:9] @ W[:9][n] + b[n]   (fp32 in, bf16 out)
// ---------------------------------------------------------------------------
__launch_bounds__(256)
__global__ void enc_kernel(const float* __restrict__ x, const float* __restrict__ W,
                           const float* __restrict__ bias, u16* __restrict__ h) {
  const size_t i = (size_t)blockIdx.x * 256 + threadIdx.x;  // 19200*1024
  const int m = (int)(i >> 10), n = (int)(i & 1023);
  const float* xr = x + (size_t)m * 9;
  float acc = bias[n];
#pragma unroll
  for (int f = 0; f < 9; ++f) acc += xr[f] * W[f * 1024 + n];
  h[i] = f2bf(acc);
}

// ---------------------------------------------------------------------------
// GEMM: C[m][n] = A[m][:] . Bt[n][:] (+bias, +residual / +ELU), K=1024 fixed.
// 128x128 tile, BK=64, 4 waves (2x2), mfma_f32_16x16x32_bf16, global_load_lds.
// Cross-validated: r1/r2/r3 (two MFMA variants vs scalar) bit-identical.
// EPI: 0 = bias; 1 = bias + residual R; 2 = bias + ELU
// ---------------------------------------------------------------------------
template <int EPI>
__launch_bounds__(256)
__global__ void gemm_bt(const u16* __restrict__ A, int lda,
                        const u16* __restrict__ Bt,
                        const float* __restrict__ bias,
                        const u16* __restrict__ R, int ldr,
                        u16* __restrict__ C, int ldc) {
  constexpr int K = 1024;
  __shared__ u16 As[128 * 64];
  __shared__ u16 Bs[128 * 64];
  const int tid = threadIdx.x;
  const int lane = tid & 63;
  const int w = tid >> 6;
  const int wr = w >> 1, wc = w & 1;
  const int m0 = blockIdx.y * 128, n0 = blockIdx.x * 128;

  floatx4 acc[4][4];
#pragma unroll
  for (int i = 0; i < 4; ++i)
#pragma unroll
    for (int j = 0; j < 4; ++j) acc[i][j] = (floatx4){0.f, 0.f, 0.f, 0.f};

  const u16* Ab = A + (size_t)m0 * lda;
  const u16* Bb = Bt + (size_t)n0 * K;

  for (int k0 = 0; k0 < K; k0 += 64) {
#pragma unroll
    for (int p = 0; p < 4; ++p) {
      const int o = p * 4096 + tid * 16;  // byte offset into 16KB tile
      const int row = o >> 7;             // 128 B per row
      const int ke = (o & 127) >> 1;      // elem offset in row
      __builtin_amdgcn_global_load_lds((const AS1 void*)(Ab + (size_t)row * lda + (k0 + ke)),
                                       (AS3 void*)((char*)As + o), 16, 0, 0);
      __builtin_amdgcn_global_load_lds((const AS1 void*)(Bb + (size_t)row * K + (k0 + ke)),
                                       (AS3 void*)((char*)Bs + o), 16, 0, 0);
    }
    __syncthreads();
#pragma unroll
    for (int ks = 0; ks < 2; ++ks) {
      shortx8 af[4], bfr[4];
#pragma unroll
      for (int i = 0; i < 4; ++i) {
        const int ar = wr * 64 + i * 16 + (lane & 15);
        af[i] = *(const shortx8*)&As[ar * 64 + ks * 32 + (lane >> 4) * 8];
        const int br = wc * 64 + i * 16 + (lane & 15);
        bfr[i] = *(const shortx8*)&Bs[br * 64 + ks * 32 + (lane >> 4) * 8];
      }
#pragma unroll
      for (int i = 0; i < 4; ++i)
#pragma unroll
        for (int j = 0; j < 4; ++j)
          acc[i][j] = __builtin_amdgcn_mfma_f32_16x16x32_bf16(af[i], bfr[j], acc[i][j], 0, 0, 0);
    }
    __syncthreads();
  }

  // epilogue: C/D layout col=lane&15, row=(lane>>4)*4+r  [m89 + r2 probe-confirmed]
  const int lr = (lane >> 4) * 4, lc = lane & 15;
#pragma unroll
  for (int i = 0; i < 4; ++i) {
#pragma unroll
    for (int j = 0; j < 4; ++j) {
      const int col = n0 + wc * 64 + j * 16 + lc;
      const float bv = bias[col];
#pragma unroll
      for (int r = 0; r < 4; ++r) {
        const int row = m0 + wr * 64 + i * 16 + lr + r;
        float v = acc[i][j][r] + bv;
        if (EPI == 1) v += bf2f(R[(size_t)row * ldr + col]);
        if (EPI == 2) v = v > 0.f ? v : expm1f(v);
        C[(size_t)row * ldc + col] = f2bf(v);
      }
    }
  }
}

// ---------------------------------------------------------------------------
// Attention: one wave per (b,h,s) row. qkv layout [b*600+s][3072] (q|k|v each h*64+d).
// Output a[b*600+s][d*16 + h]  (torch stack(dim=-1) interleave).
// ---------------------------------------------------------------------------
__launch_bounds__(256)
__global__ void attn_kernel(const u16* __restrict__ qkv, u16* __restrict__ aout) {
  const int blk = blockIdx.x;
  const int bh = blk / 150, rb = blk % 150;
  const int b = bh >> 4, h = bh & 15;
  const int wv = threadIdx.x >> 6, lane = threadIdx.x & 63;
  const int s = rb * 4 + wv;

  __shared__ float q_sh[4][64];
  __shared__ float p_sh[4][640];

  const size_t rowbase = ((size_t)(b * 600 + s)) * 3072 + (size_t)h * 64;
  q_sh[wv][lane] = bf2f(qkv[rowbase + lane]);
  __syncthreads();

  const u16* kbase = qkv + (size_t)b * 600 * 3072 + 1024 + h * 64;
  const u16* vbase = kbase + 1024;

  float sc[10];
  float mx = -1e30f;
#pragma unroll
  for (int j = 0; j < 10; ++j) {
    const int t = j * 64 + lane;
    float s_val = -1e30f;
    if (t < 600) {
      const uintx4* kr = (const uintx4*)(kbase + (size_t)t * 3072);
      float acc = 0.f;
#pragma unroll
      for (int c = 0; c < 8; ++c) {
        uintx4 kvv = kr[c];
#pragma unroll
        for (int q = 0; q < 4; ++q) {
          u32 wd = kvv[q];
          float k0 = __builtin_bit_cast(float, wd << 16);
          float k1 = __builtin_bit_cast(float, wd & 0xffff0000u);
          acc += q_sh[wv][c * 8 + q * 2] * k0;
          acc += q_sh[wv][c * 8 + q * 2 + 1] * k1;
        }
      }
      s_val = acc * 0.125f;  // 1/sqrt(64)
    }
    sc[j] = s_val;
    mx = fmaxf(mx, s_val);
  }
#pragma unroll
  for (int m = 32; m; m >>= 1) mx = fmaxf(mx, __shfl_xor(mx, m));

  float sum = 0.f;
#pragma unroll
  for (int j = 0; j < 10; ++j) {
    const int t = j * 64 + lane;
    float p = (t < 600) ? __expf(sc[j] - mx) : 0.f;
    p_sh[wv][t] = p;
    sum += p;
  }
#pragma unroll
  for (int m = 32; m; m >>= 1) sum += __shfl_xor(sum, m);
  const float inv = 1.f / sum;
  __syncthreads();

  const u16* vcol = vbase + lane;  // d = lane
  float acc = 0.f;
  for (int t = 0; t < 600; t += 4) {
    float4 pv = *(const float4*)&p_sh[wv][t];
    acc += pv.x * bf2f(vcol[(size_t)t * 3072]);
    acc += pv.y * bf2f(vcol[(size_t)(t + 1) * 3072]);
    acc += pv.z * bf2f(vcol[(size_t)(t + 2) * 3072]);
    acc += pv.w * bf2f(vcol[(size_t)(t + 3) * 3072]);
  }
  aout[((size_t)(b * 600 + s)) * 1024 + lane * 16 + h] = f2bf(acc * inv);
}

// ---------------------------------------------------------------------------
// LayerNorm over 1024 (strided rows): one block per row, biased var, eps 1e-5.
// g, be fp32.
// ---------------------------------------------------------------------------
__launch_bounds__(256)
__global__ void ln_kernel(const u16* __restrict__ y, int ldy,
                          const float* __restrict__ g, const float* __restrict__ be,
                          u16* __restrict__ o, int ldo) {
  const int row = blockIdx.x, tid = threadIdx.x;
  const int lane = tid & 63, wv = tid >> 6;
  const u16* yr = y + (size_t)row * ldy;
  const int c = tid * 4;
  float v0 = bf2f(yr[c]), v1 = bf2f(yr[c + 1]);
  float v2 = bf2f(yr[c + 2]), v3 = bf2f(yr[c + 3]);
  float s = v0 + v1 + v2 + v3;
  float q = v0 * v0 + v1 * v1 + v2 * v2 + v3 * v3;
#pragma unroll
  for (int m = 32; m; m >>= 1) {
    s += __shfl_xor(s, m);
    q += __shfl_xor(q, m);
  }
  __shared__ float red[2][4];
  if (lane == 0) {
    red[0][wv] = s;
    red[1][wv] = q;
  }
  __syncthreads();
  s = red[0][0] + red[0][1] + red[0][2] + red[0][3];
  q = red[1][0] + red[1][1] + red[1][2] + red[1][3];
  const float mu = s * (1.f / 1024.f);
  const float var = q * (1.f / 1024.f) - mu * mu;
  const float rstd = rsqrtf(var + 1e-5f);
  u16* orow = o + (size_t)row * ldo;
  orow[c]     = f2bf((v0 - mu) * rstd * g[c] + be[c]);
  orow[c + 1] = f2bf((v1 - mu) * rstd * g[c + 1] + be[c + 1]);
  orow[c + 2] = f2bf((v2 - mu) * rstd * g[c + 2] + be[c + 2]);
  orow[c + 3] = f2bf((v3 - mu) * rstd * g[c + 3] + be[c + 3]);
}

// ---------------------------------------------------------------------------
// out: out[m][f] = h[m][:] . outW[:][f] + outb[f], f<9. One wave per row.
// OUTPUT IS fp32 (reference output dtype = float32).
// ---------------------------------------------------------------------------
__launch_bounds__(256)
__global__ void out_kernel(const u16* __restrict__ h, const float* __restrict__ W,
                           const float* __restrict__ bias, float* __restrict__ out) {
  const int m = blockIdx.x * 4 + (threadIdx.x >> 6);
  const int lane = threadIdx.x & 63;
  float acc[9];
#pragma unroll
  for (int f = 0; f < 9; ++f) acc[f] = 0.f;
  const u16* hr = h + (size_t)m * 1024;
#pragma unroll 4
  for (int j = 0; j < 16; ++j) {
    const int k = lane + j * 64;
    const float hv = bf2f(hr[k]);
    const float* wr = W + (size_t)k * 9;
#pragma unroll
    for (int f = 0; f < 9; ++f) acc[f] += hv * wr[f];
  }
#pragma unroll
  for (int f = 0; f < 9; ++f)
#pragma unroll
    for (int mm = 32; mm; mm >>= 1) acc[f] += __shfl_xor(acc[f], mm);
  if (lane < 9) out[(size_t)m * 9 + lane] = acc[lane] + bias[lane];
}

// ---------------------------------------------------------------------------
extern "C" void kernel_launch(void* const* d_in, const int* in_sizes, int n_in,
                              void* d_out, int out_size, void* d_ws, size_t ws_size,
                              hipStream_t stream) {
  (void)in_sizes; (void)n_in; (void)out_size; (void)ws_size;
  // Inputs are fp32 (reference dtypes); output is fp32 (reference output dtype).
  const float* x     = (const float*)d_in[0];
  const float* encW  = (const float*)d_in[1];
  const float* encB  = (const float*)d_in[2];
  const float* Wq    = (const float*)d_in[3];
  const float* bq    = (const float*)d_in[4];
  const float* Wk    = (const float*)d_in[5];
  const float* bk    = (const float*)d_in[6];
  const float* Wv    = (const float*)d_in[7];
  const float* bv    = (const float*)d_in[8];
  const float* Wo    = (const float*)d_in[9];
  const float* bo    = (const float*)d_in[10];
  const float* W1    = (const float*)d_in[11];
  const float* b1    = (const float*)d_in[12];
  const float* W2    = (const float*)d_in[13];
  const float* b2    = (const float*)d_in[14];
  const float* ln1w  = (const float*)d_in[15];
  const float* ln1b  = (const float*)d_in[16];
  const float* ln2w  = (const float*)d_in[17];
  const float* ln2b  = (const float*)d_in[18];
  const float* outW  = (const float*)d_in[19];
  const float* outB  = (const float*)d_in[20];
  float* out = (float*)d_out;

  char* ws = (char*)d_ws;
  size_t off = 0;
  auto alloc = [&](size_t bytes) -> void* {
    void* p = ws + off;
    off += (bytes + 255) & ~(size_t)255;
    return p;
  };
  u16* h    = (u16*)alloc(19660800ull * 2);   // [19200][1024]
  u16* qkv  = (u16*)alloc(58982400ull * 2);   // [19200][3072]
  u16* abuf = (u16*)alloc(19660800ull * 2);   // ctx flat [19200][1024]
  u16* Bqkv = (u16*)alloc(6291456ull * 2);    // [2][3072][1024]
  u16* Bwo  = (u16*)alloc(2097152ull * 2);    // [2][1024][1024] transposed
  u16* Bw1  = (u16*)alloc(2097152ull * 2);
  u16* Bw2  = (u16*)alloc(2097152ull * 2);
  float* bqkv = (float*)alloc(6144ull * 4);   // [2][3072] fp32
  // column-slot aliases inside qkv (stride 3072), reusing dead q/k/v slots:
  u16* ybuf = qkv;          // q-slot: Wo-gemm output (q dead after attention)
  u16* x1   = qkv + 1024;   // k-slot: ln1 output
  u16* mid  = qkv + 2048;   // v-slot: fc2/ELU output
  u16* y2   = abuf;         // dense: fc1 output (+x1 residual); abuf dead by then

  pack_qkv<<<24576, 256, 0, stream>>>(Wq, Wk, Wv, bq, bk, bv, Bqkv, bqkv);
  pack_t<<<8192, 256, 0, stream>>>(Wo, Bwo);
  pack_t<<<8192, 256, 0, stream>>>(W1, Bw1);
  pack_t<<<8192, 256, 0, stream>>>(W2, Bw2);
  enc_kernel<<<76800, 256, 0, stream>>>(x, encW, encB, h);

  for (int l = 0; l < 2; ++l) {
    gemm_bt<0><<<dim3(24, 150), 256, 0, stream>>>(
        h, 1024, Bqkv + (size_t)l * 3145728, bqkv + l * 3072, nullptr, 0, qkv, 3072);
    attn_kernel<<<76800, 256, 0, stream>>>(qkv, abuf);
    gemm_bt<1><<<dim3(8, 150), 256, 0, stream>>>(
        abuf, 1024, Bwo + (size_t)l * 1048576, bo + l * 1024, h, 1024, ybuf, 3072);
    ln_kernel<<<19200, 256, 0, stream>>>(ybuf, 3072, ln1w + l * 1024, ln1b + l * 1024, x1, 3072);
    gemm_bt<2><<<dim3(8, 150), 256, 0, stream>>>(
        x1, 3072, Bw2 + (size_t)l * 1048576, b2 + l * 1024, nullptr, 0, mid, 3072);
    gemm_bt<1><<<dim3(8, 150), 256, 0, stream>>>(
        mid, 3072, Bw1 + (size_t)l * 1048576, b1 + l * 1024, x1, 3072, y2, 1024);
    ln_kernel<<<19200, 256, 0, stream>>>(y2, 1024, ln2w + l * 1024, ln2b + l * 1024, h, 1024);
  }
  out_kernel<<<4800, 256, 0, stream>>>(h, outW, outB, out);
}

// Round 6
// 1427.505 us; speedup vs baseline: 12.6671x; 12.6671x over previous
//
#include <hip/hip_runtime.h>

typedef unsigned short u16;
typedef unsigned int u32;
typedef __attribute__((ext_vector_type(8))) short shortx8;
typedef __attribute__((ext_vector_type(4))) float floatx4;
typedef __attribute__((ext_vector_type(4))) u32 uintx4;

#define AS1 __attribute__((address_space(1)))
#define AS3 __attribute__((address_space(3)))

__device__ __forceinline__ float bf2f(u16 u) {
  return __builtin_bit_cast(float, ((u32)u) << 16);
}
__device__ __forceinline__ u16 f2bf(float f) {
  u32 i = __builtin_bit_cast(u32, f);
  u32 r = (i + 0x7fffu + ((i >> 16) & 1u)) >> 16;  // RNE
  return (u16)r;
}

// ---------------------------------------------------------------------------
// Weight packing: QKV (fp32) -> Bt[l][n][k] bf16 (n = which*1024 + h*64 + d),
// bias fp32.
// ---------------------------------------------------------------------------
__launch_bounds__(256)
__global__ void pack_qkv(const float* __restrict__ Wq, const float* __restrict__ Wk,
                         const float* __restrict__ Wv, const float* __restrict__ bq,
                         const float* __restrict__ bk, const float* __restrict__ bv,
                         u16* __restrict__ Bt, float* __restrict__ bias) {
  const size_t i = (size_t)blockIdx.x * 256 + threadIdx.x;  // [l][n][k], 2*3072*1024
  const int k = (int)(i & 1023);
  const size_t r = i >> 10;
  const int n = (int)(r % 3072);
  const int l = (int)(r / 3072);
  const int which = n >> 10;
  const int nn = n & 1023;
  const int hh = nn >> 6, dd = nn & 63;
  const float* src = (which == 0) ? Wq : (which == 1) ? Wk : Wv;
  const float* srcb = (which == 0) ? bq : (which == 1) ? bk : bv;
  float v = src[(((size_t)l * 16 + hh) * 1024 + k) * 64 + dd];  // W[l][h][k][d]
  Bt[i] = f2bf(v);
  if (k == 0) bias[(size_t)l * 3072 + n] = srcb[(size_t)l * 1024 + nn];
}

// W[l][k][n] fp32 -> Bt[l][n][k] bf16   (for Wo, W1, W2)
__launch_bounds__(256)
__global__ void pack_t(const float* __restrict__ W, u16* __restrict__ Bt) {
  const size_t i = (size_t)blockIdx.x * 256 + threadIdx.x;  // [l][n][k], 2*1024*1024
  const int k = (int)(i & 1023);
  const size_t r = i >> 10;
  const int n = (int)(r & 1023);
  const int l = (int)(r >> 10);
  Bt[i] = f2bf(W[((size_t)l * 1024 + k) * 1024 + n]);
}

// ---------------------------------------------------------------------------
// enc_in: h[m][n] = x[m][:9] @ W[:9][n] + b[n]   (fp32 in, bf16 out)
// ---------------------------------------------------------------------------
__launch_bounds__(256)
__global__ void enc_kernel(const float* __restrict__ x, const float* __restrict__ W,
                           const float* __restrict__ bias, u16* __restrict__ h) {
  const size_t i = (size_t)blockIdx.x * 256 + threadIdx.x;  // 19200*1024
  const int m = (int)(i >> 10), n = (int)(i & 1023);
  const float* xr = x + (size_t)m * 9;
  float acc = bias[n];
#pragma unroll
  for (int f = 0; f < 9; ++f) acc += xr[f] * W[f * 1024 + n];
  h[i] = f2bf(acc);
}

// ---------------------------------------------------------------------------
// GEMM: C[m][n] = A[m][:] . Bt[n][:] (+bias, +residual / +ELU), K=1024 fixed.
// 128x128 tile, BK=64, 4 waves (2x2), mfma_f32_16x16x32_bf16, global_load_lds.
// EPI: 0 = bias; 1 = bias + residual R; 2 = bias + ELU
// ---------------------------------------------------------------------------
template <int EPI>
__launch_bounds__(256)
__global__ void gemm_bt(const u16* __restrict__ A, int lda,
                        const u16* __restrict__ Bt,
                        const float* __restrict__ bias,
                        const u16* __restrict__ R, int ldr,
                        u16* __restrict__ C, int ldc) {
  constexpr int K = 1024;
  __shared__ u16 As[128 * 64];
  __shared__ u16 Bs[128 * 64];
  const int tid = threadIdx.x;
  const int lane = tid & 63;
  const int w = tid >> 6;
  const int wr = w >> 1, wc = w & 1;
  const int m0 = blockIdx.y * 128, n0 = blockIdx.x * 128;

  floatx4 acc[4][4];
#pragma unroll
  for (int i = 0; i < 4; ++i)
#pragma unroll
    for (int j = 0; j < 4; ++j) acc[i][j] = (floatx4){0.f, 0.f, 0.f, 0.f};

  const u16* Ab = A + (size_t)m0 * lda;
  const u16* Bb = Bt + (size_t)n0 * K;

  for (int k0 = 0; k0 < K; k0 += 64) {
#pragma unroll
    for (int p = 0; p < 4; ++p) {
      const int o = p * 4096 + tid * 16;  // byte offset into 16KB tile
      const int row = o >> 7;             // 128 B per row
      const int ke = (o & 127) >> 1;      // elem offset in row
      __builtin_amdgcn_global_load_lds((const AS1 void*)(Ab + (size_t)row * lda + (k0 + ke)),
                                       (AS3 void*)((char*)As + o), 16, 0, 0);
      __builtin_amdgcn_global_load_lds((const AS1 void*)(Bb + (size_t)row * K + (k0 + ke)),
                                       (AS3 void*)((char*)Bs + o), 16, 0, 0);
    }
    __syncthreads();
#pragma unroll
    for (int ks = 0; ks < 2; ++ks) {
      shortx8 af[4], bfr[4];
#pragma unroll
      for (int i = 0; i < 4; ++i) {
        const int ar = wr * 64 + i * 16 + (lane & 15);
        af[i] = *(const shortx8*)&As[ar * 64 + ks * 32 + (lane >> 4) * 8];
        const int br = wc * 64 + i * 16 + (lane & 15);
        bfr[i] = *(const shortx8*)&Bs[br * 64 + ks * 32 + (lane >> 4) * 8];
      }
#pragma unroll
      for (int i = 0; i < 4; ++i)
#pragma unroll
        for (int j = 0; j < 4; ++j)
          acc[i][j] = __builtin_amdgcn_mfma_f32_16x16x32_bf16(af[i], bfr[j], acc[i][j], 0, 0, 0);
    }
    __syncthreads();
  }

  // epilogue: C/D layout col=lane&15, row=(lane>>4)*4+r  [validated r1/r2/r3]
  const int lr = (lane >> 4) * 4, lc = lane & 15;
#pragma unroll
  for (int i = 0; i < 4; ++i) {
#pragma unroll
    for (int j = 0; j < 4; ++j) {
      const int col = n0 + wc * 64 + j * 16 + lc;
      const float bv = bias[col];
#pragma unroll
      for (int r = 0; r < 4; ++r) {
        const int row = m0 + wr * 64 + i * 16 + lr + r;
        float v = acc[i][j][r] + bv;
        if (EPI == 1) v += bf2f(R[(size_t)row * ldr + col]);
        if (EPI == 2) v = v > 0.f ? v : expm1f(v);
        C[(size_t)row * ldc + col] = f2bf(v);
      }
    }
  }
}

// ---------------------------------------------------------------------------
// MFMA flash attention. Block = 4 waves, one (b,h), 64 q-rows (16/wave).
// grid (x=qt 10, y=bh 512). qkv rows [b*600+s][3072] (q|k|v, each h*64+d).
// K-chunks of 128: K_ld row-major [128][72] (padded), Vt transposed [64][136],
// P via wave-private LDS [16][136] (C/D-layout -> A-frag-layout transpose).
// Online softmax in regs: S-acc lane holds (q=(lane>>4)*4+r, t=lane&15).
// Output a[b*600+s][d*16 + h].
// ---------------------------------------------------------------------------
__launch_bounds__(256)
__global__ void attn_mfma(const u16* __restrict__ qkv, u16* __restrict__ aout) {
  const int qt = blockIdx.x, bh = blockIdx.y;
  const int b = bh >> 4, h = bh & 15;
  const int tid = threadIdx.x, lane = tid & 63, w = tid >> 6;
  const int g = lane >> 4, lq = lane & 15;

  __shared__ u16 K_ld[128 * 72];
  __shared__ u16 Vt[64 * 136];
  __shared__ u16 P_ld[4][16 * 136];

  const size_t bbase = (size_t)b * 600 * 3072;
  const int q0 = qt * 64 + w * 16;

  // Q fragments: row = lane&15, k(d) = ks*32 + g*8 + j
  shortx8 aq[2];
  {
    const int s = q0 + lq;
    if (s < 600) {
      const u16* qp = qkv + bbase + (size_t)s * 3072 + h * 64 + g * 8;
      aq[0] = *(const shortx8*)qp;
      aq[1] = *(const shortx8*)(qp + 32);
    } else {
      aq[0] = (shortx8){0, 0, 0, 0, 0, 0, 0, 0};
      aq[1] = (shortx8){0, 0, 0, 0, 0, 0, 0, 0};
    }
  }

  floatx4 Oa[4];
#pragma unroll
  for (int db = 0; db < 4; ++db) Oa[db] = (floatx4){0.f, 0.f, 0.f, 0.f};
  float m[4], l[4];
#pragma unroll
  for (int r = 0; r < 4; ++r) { m[r] = -1e30f; l[r] = 0.f; }

  for (int ch = 0; ch < 5; ++ch) {
    const int t0 = ch * 128;
    __syncthreads();  // protect K_ld/Vt from previous chunk's readers
    {
      const int tloc = tid >> 1, dhalf = (tid & 1) * 32;
      const int tg = t0 + tloc;
      if (tg < 600) {
        const u16* kp = qkv + bbase + (size_t)tg * 3072 + 1024 + h * 64 + dhalf;
        const u16* vp = kp + 1024;
#pragma unroll
        for (int c = 0; c < 4; ++c)
          *(uintx4*)&K_ld[tloc * 72 + dhalf + c * 8] = *(const uintx4*)(kp + c * 8);
#pragma unroll
        for (int c = 0; c < 4; ++c) {
          shortx8 vv = *(const shortx8*)(vp + c * 8);
#pragma unroll
          for (int e = 0; e < 8; ++e)
            Vt[(dhalf + c * 8 + e) * 136 + tloc] = (u16)vv[e];
        }
      } else {
        const uintx4 z4 = (uintx4){0, 0, 0, 0};
#pragma unroll
        for (int c = 0; c < 4; ++c)
          *(uintx4*)&K_ld[tloc * 72 + dhalf + c * 8] = z4;
#pragma unroll
        for (int c = 0; c < 4; ++c)
#pragma unroll
          for (int e = 0; e < 8; ++e)
            Vt[(dhalf + c * 8 + e) * 136 + tloc] = 0;
      }
    }
    __syncthreads();

    // QK^T: S[jb] covers t = t0 + jb*16 + lq, q = q0 + g*4 + r
    floatx4 S[8];
#pragma unroll
    for (int jb = 0; jb < 8; ++jb) {
      S[jb] = (floatx4){0.f, 0.f, 0.f, 0.f};
#pragma unroll
      for (int ks = 0; ks < 2; ++ks) {
        shortx8 bk = *(const shortx8*)&K_ld[(jb * 16 + lq) * 72 + ks * 32 + g * 8];
        S[jb] = __builtin_amdgcn_mfma_f32_16x16x32_bf16(aq[ks], bk, S[jb], 0, 0, 0);
      }
    }
    // scale + mask invalid t
#pragma unroll
    for (int jb = 0; jb < 8; ++jb) {
      const int tg = t0 + jb * 16 + lq;
      const bool ok = tg < 600;
#pragma unroll
      for (int r = 0; r < 4; ++r) S[jb][r] = ok ? S[jb][r] * 0.125f : -1e30f;
    }

    // online softmax: row max (reduce over jb then lq-group)
    float scale[4];
#pragma unroll
    for (int r = 0; r < 4; ++r) {
      float v = S[0][r];
#pragma unroll
      for (int jb = 1; jb < 8; ++jb) v = fmaxf(v, S[jb][r]);
      v = fmaxf(v, __shfl_xor(v, 1));
      v = fmaxf(v, __shfl_xor(v, 2));
      v = fmaxf(v, __shfl_xor(v, 4));
      v = fmaxf(v, __shfl_xor(v, 8));
      const float mn = fmaxf(m[r], v);
      scale[r] = __expf(m[r] - mn);
      m[r] = mn;
      l[r] *= scale[r];
    }
#pragma unroll
    for (int db = 0; db < 4; ++db)
#pragma unroll
      for (int r = 0; r < 4; ++r) Oa[db][r] *= scale[r];

    // P = exp(S - m): accumulate row sums, write bf16 to wave-private LDS
    float sums[4] = {0.f, 0.f, 0.f, 0.f};
#pragma unroll
    for (int jb = 0; jb < 8; ++jb)
#pragma unroll
      for (int r = 0; r < 4; ++r) {
        const float p = __expf(S[jb][r] - m[r]);
        sums[r] += p;
        P_ld[w][(g * 4 + r) * 136 + jb * 16 + lq] = f2bf(p);
      }
#pragma unroll
    for (int r = 0; r < 4; ++r) {
      float v = sums[r];
      v += __shfl_xor(v, 1);
      v += __shfl_xor(v, 2);
      v += __shfl_xor(v, 4);
      v += __shfl_xor(v, 8);
      l[r] += v;
    }

    // PV: A = P (row q=lane&15, k=t), B = Vt (col d=lane&15, k=t)
#pragma unroll
    for (int ks = 0; ks < 4; ++ks) {
      shortx8 ap = *(const shortx8*)&P_ld[w][lq * 136 + ks * 32 + g * 8];
#pragma unroll
      for (int db = 0; db < 4; ++db) {
        shortx8 bv = *(const shortx8*)&Vt[(db * 16 + lq) * 136 + ks * 32 + g * 8];
        Oa[db] = __builtin_amdgcn_mfma_f32_16x16x32_bf16(ap, bv, Oa[db], 0, 0, 0);
      }
    }
  }

  // epilogue: O row q = q0 + g*4 + r, col d = db*16 + lq; out col = d*16 + h
#pragma unroll
  for (int r = 0; r < 4; ++r) {
    const int sg = q0 + g * 4 + r;
    if (sg < 600) {
      const float inv = 1.f / l[r];
      u16* orow = aout + ((size_t)(b * 600 + sg)) * 1024 + h;
#pragma unroll
      for (int db = 0; db < 4; ++db)
        orow[(size_t)(db * 16 + lq) * 16] = f2bf(Oa[db][r] * inv);
    }
  }
}

// ---------------------------------------------------------------------------
// LayerNorm over 1024 (strided rows): one block per row, biased var, eps 1e-5.
// ---------------------------------------------------------------------------
__launch_bounds__(256)
__global__ void ln_kernel(const u16* __restrict__ y, int ldy,
                          const float* __restrict__ g, const float* __restrict__ be,
                          u16* __restrict__ o, int ldo) {
  const int row = blockIdx.x, tid = threadIdx.x;
  const int lane = tid & 63, wv = tid >> 6;
  const u16* yr = y + (size_t)row * ldy;
  const int c = tid * 4;
  float v0 = bf2f(yr[c]), v1 = bf2f(yr[c + 1]);
  float v2 = bf2f(yr[c + 2]), v3 = bf2f(yr[c + 3]);
  float s = v0 + v1 + v2 + v3;
  float q = v0 * v0 + v1 * v1 + v2 * v2 + v3 * v3;
#pragma unroll
  for (int m = 32; m; m >>= 1) {
    s += __shfl_xor(s, m);
    q += __shfl_xor(q, m);
  }
  __shared__ float red[2][4];
  if (lane == 0) {
    red[0][wv] = s;
    red[1][wv] = q;
  }
  __syncthreads();
  s = red[0][0] + red[0][1] + red[0][2] + red[0][3];
  q = red[1][0] + red[1][1] + red[1][2] + red[1][3];
  const float mu = s * (1.f / 1024.f);
  const float var = q * (1.f / 1024.f) - mu * mu;
  const float rstd = rsqrtf(var + 1e-5f);
  u16* orow = o + (size_t)row * ldo;
  orow[c]     = f2bf((v0 - mu) * rstd * g[c] + be[c]);
  orow[c + 1] = f2bf((v1 - mu) * rstd * g[c + 1] + be[c + 1]);
  orow[c + 2] = f2bf((v2 - mu) * rstd * g[c + 2] + be[c + 2]);
  orow[c + 3] = f2bf((v3 - mu) * rstd * g[c + 3] + be[c + 3]);
}

// ---------------------------------------------------------------------------
// out: out[m][f] = h[m][:] . outW[:][f] + outb[f], f<9. One wave per row. fp32 out.
// ---------------------------------------------------------------------------
__launch_bounds__(256)
__global__ void out_kernel(const u16* __restrict__ h, const float* __restrict__ W,
                           const float* __restrict__ bias, float* __restrict__ out) {
  const int m = blockIdx.x * 4 + (threadIdx.x >> 6);
  const int lane = threadIdx.x & 63;
  float acc[9];
#pragma unroll
  for (int f = 0; f < 9; ++f) acc[f] = 0.f;
  const u16* hr = h + (size_t)m * 1024;
#pragma unroll 4
  for (int j = 0; j < 16; ++j) {
    const int k = lane + j * 64;
    const float hv = bf2f(hr[k]);
    const float* wr = W + (size_t)k * 9;
#pragma unroll
    for (int f = 0; f < 9; ++f) acc[f] += hv * wr[f];
  }
#pragma unroll
  for (int f = 0; f < 9; ++f)
#pragma unroll
    for (int mm = 32; mm; mm >>= 1) acc[f] += __shfl_xor(acc[f], mm);
  if (lane < 9) out[(size_t)m * 9 + lane] = acc[lane] + bias[lane];
}

// ---------------------------------------------------------------------------
extern "C" void kernel_launch(void* const* d_in, const int* in_sizes, int n_in,
                              void* d_out, int out_size, void* d_ws, size_t ws_size,
                              hipStream_t stream) {
  (void)in_sizes; (void)n_in; (void)out_size; (void)ws_size;
  const float* x     = (const float*)d_in[0];
  const float* encW  = (const float*)d_in[1];
  const float* encB  = (const float*)d_in[2];
  const float* Wq    = (const float*)d_in[3];
  const float* bq    = (const float*)d_in[4];
  const float* Wk    = (const float*)d_in[5];
  const float* bk    = (const float*)d_in[6];
  const float* Wv    = (const float*)d_in[7];
  const float* bv    = (const float*)d_in[8];
  const float* Wo    = (const float*)d_in[9];
  const float* bo    = (const float*)d_in[10];
  const float* W1    = (const float*)d_in[11];
  const float* b1    = (const float*)d_in[12];
  const float* W2    = (const float*)d_in[13];
  const float* b2    = (const float*)d_in[14];
  const float* ln1w  = (const float*)d_in[15];
  const float* ln1b  = (const float*)d_in[16];
  const float* ln2w  = (const float*)d_in[17];
  const float* ln2b  = (const float*)d_in[18];
  const float* outW  = (const float*)d_in[19];
  const float* outB  = (const float*)d_in[20];
  float* out = (float*)d_out;

  char* ws = (char*)d_ws;
  size_t off = 0;
  auto alloc = [&](size_t bytes) -> void* {
    void* p = ws + off;
    off += (bytes + 255) & ~(size_t)255;
    return p;
  };
  u16* h    = (u16*)alloc(19660800ull * 2);   // [19200][1024]
  u16* qkv  = (u16*)alloc(58982400ull * 2);   // [19200][3072]
  u16* abuf = (u16*)alloc(19660800ull * 2);   // ctx flat [19200][1024]
  u16* Bqkv = (u16*)alloc(6291456ull * 2);    // [2][3072][1024]
  u16* Bwo  = (u16*)alloc(2097152ull * 2);    // [2][1024][1024] transposed
  u16* Bw1  = (u16*)alloc(2097152ull * 2);
  u16* Bw2  = (u16*)alloc(2097152ull * 2);
  float* bqkv = (float*)alloc(6144ull * 4);   // [2][3072] fp32
  // column-slot aliases inside qkv (stride 3072), reusing dead q/k/v slots:
  u16* ybuf = qkv;          // q-slot: Wo-gemm output (q dead after attention)
  u16* x1   = qkv + 1024;   // k-slot: ln1 output
  u16* mid  = qkv + 2048;   // v-slot: fc2/ELU output
  u16* y2   = abuf;         // dense: fc1 output (+x1 residual); abuf dead by then

  pack_qkv<<<24576, 256, 0, stream>>>(Wq, Wk, Wv, bq, bk, bv, Bqkv, bqkv);
  pack_t<<<8192, 256, 0, stream>>>(Wo, Bwo);
  pack_t<<<8192, 256, 0, stream>>>(W1, Bw1);
  pack_t<<<8192, 256, 0, stream>>>(W2, Bw2);
  enc_kernel<<<76800, 256, 0, stream>>>(x, encW, encB, h);

  for (int l = 0; l < 2; ++l) {
    gemm_bt<0><<<dim3(24, 150), 256, 0, stream>>>(
        h, 1024, Bqkv + (size_t)l * 3145728, bqkv + l * 3072, nullptr, 0, qkv, 3072);
    attn_mfma<<<dim3(10, 512), 256, 0, stream>>>(qkv, abuf);
    gemm_bt<1><<<dim3(8, 150), 256, 0, stream>>>(
        abuf, 1024, Bwo + (size_t)l * 1048576, bo + l * 1024, h, 1024, ybuf, 3072);
    ln_kernel<<<19200, 256, 0, stream>>>(ybuf, 3072, ln1w + l * 1024, ln1b + l * 1024, x1, 3072);
    gemm_bt<2><<<dim3(8, 150), 256, 0, stream>>>(
        x1, 3072, Bw2 + (size_t)l * 1048576, b2 + l * 1024, nullptr, 0, mid, 3072);
    gemm_bt<1><<<dim3(8, 150), 256, 0, stream>>>(
        mid, 3072, Bw1 + (size_t)l * 1048576, b1 + l * 1024, x1, 3072, y2, 1024);
    ln_kernel<<<19200, 256, 0, stream>>>(y2, 1024, ln2w + l * 1024, ln2b + l * 1024, h, 1024);
  }
  out_kernel<<<4800, 256, 0, stream>>>(h, outW, outB, out);
}